// Round 5
// baseline (1282.750 us; speedup 1.0000x reference)
//
#include <hip/hip_runtime.h>
#include <hip/hip_bf16.h>

#define NN 50000
#define EE 800000
#define DD 100
#define HH 16
#define CC 40
#define NCELL 12
#define NB_SCAN 49   // ceil(50000/1024)

// ---------------- graph preprocessing ----------------

__global__ __launch_bounds__(256) void k_hist(const int* __restrict__ er, int* __restrict__ cnt) {
    int e = blockIdx.x * 256 + threadIdx.x;
    if (e < EE) atomicAdd(&cnt[er[e]], 1);
}

__global__ __launch_bounds__(256) void k_dinv(const int* __restrict__ cnt, float* __restrict__ dinv) {
    int i = blockIdx.x * 256 + threadIdx.x;
    if (i < NN) dinv[i] = rsqrtf((float)(cnt[i] + 1));   // +1 self loop
}

// two-level scan: per-block exclusive scan + block totals
__global__ __launch_bounds__(1024) void k_scan1(const int* __restrict__ cnt, int* __restrict__ rp,
                                                int* __restrict__ bsum) {
    __shared__ int lds[1024];
    int t = threadIdx.x, i = blockIdx.x * 1024 + t;
    int v = (i < NN) ? cnt[i] : 0;
    lds[t] = v;
    __syncthreads();
    #pragma unroll
    for (int off = 1; off < 1024; off <<= 1) {
        int x = lds[t];
        int y = (t >= off) ? lds[t - off] : 0;
        __syncthreads();
        lds[t] = x + y;
        __syncthreads();
    }
    if (i < NN) rp[i] = lds[t] - v;           // local exclusive
    if (t == 1023) bsum[blockIdx.x] = lds[1023];
}

__global__ __launch_bounds__(64) void k_scan2(int* __restrict__ bsum) {
    int t = threadIdx.x;
    int orig = (t < NB_SCAN) ? bsum[t] : 0;
    int v = orig;
    #pragma unroll
    for (int off = 1; off < 64; off <<= 1) {
        int y = __shfl_up(v, off);
        if (t >= off) v += y;
    }
    if (t < NB_SCAN) bsum[t] = v - orig;      // exclusive
    if (t == NB_SCAN - 1) bsum[NB_SCAN] = v;  // total
}

__global__ __launch_bounds__(256) void k_scan3(int* __restrict__ rp, int* __restrict__ cursor,
                                               const int* __restrict__ bsum) {
    int i = blockIdx.x * 256 + threadIdx.x;
    if (i < NN) {
        int v = rp[i] + bsum[i >> 10];
        rp[i] = v;
        cursor[i] = v;
    }
    if (i == 0) rp[NN] = bsum[NB_SCAN];
}

__global__ __launch_bounds__(256) void k_fill(const int* __restrict__ er, const int* __restrict__ ec,
                                              const float* __restrict__ dinv, int* __restrict__ cursor,
                                              int* __restrict__ ci, float* __restrict__ cv) {
    int e = blockIdx.x * 256 + threadIdx.x;
    if (e >= EE) return;
    int r = er[e], c = ec[e];
    int p = atomicAdd(&cursor[r], 1);
    ci[p] = c;
    cv[p] = dinv[r] * dinv[c];
}

// ---------------- row L2 normalize ----------------
__global__ __launch_bounds__(256) void k_norm(const float* __restrict__ x, float* __restrict__ xn) {
    int wid = (blockIdx.x * 256 + threadIdx.x) >> 6;
    int lane = threadIdx.x & 63;
    if (wid >= NN) return;
    const size_t base = (size_t)wid * DD;
    float a = x[base + lane];
    float b = (lane < DD - 64) ? x[base + 64 + lane] : 0.f;
    float ss = a * a + b * b;
    #pragma unroll
    for (int off = 1; off < 64; off <<= 1) ss += __shfl_xor(ss, off);
    float inv = 1.f / fmaxf(sqrtf(ss), 1e-12f);
    xn[base + lane] = a * inv;
    if (lane < DD - 64) xn[base + 64 + lane] = b * inv;
}

// ---------------- SpMM with strides/offsets, wave per row, ci/cv prefetch ----------------
template <int F>
__global__ __launch_bounds__(256) void k_spmm(const int* __restrict__ rp, const int* __restrict__ ci,
                                              const float* __restrict__ cv, const float* __restrict__ dinv,
                                              const float* __restrict__ in, int ins, int ioff,
                                              float* __restrict__ out, int outs) {
    constexpr int J = (F + 63) / 64;
    int wid = (blockIdx.x * 256 + threadIdx.x) >> 6;
    int lane = threadIdx.x & 63;
    if (wid >= NN) return;
    const float* ib = in + ioff;
    float d = dinv[wid];
    float sw = d * d;
    float acc[J];
    #pragma unroll
    for (int j = 0; j < J; j++) {
        int f = lane + 64 * j;
        acc[j] = (f < F) ? sw * ib[(size_t)wid * ins + f] : 0.f;
    }
    int s = rp[wid], e = rp[wid + 1];
    int p = s;
    int cA = 0; float vA = 0.f;
    if (p < e) { cA = ci[p]; vA = cv[p]; }
    while (p < e) {
        int pn = p + 1;
        int cB = 0; float vB = 0.f;
        if (pn < e) { cB = ci[pn]; vB = cv[pn]; }     // prefetch next edge
        size_t b = (size_t)cA * ins;
        #pragma unroll
        for (int j = 0; j < J; j++) {
            int f = lane + 64 * j;
            if (f < F) acc[j] += vA * ib[b + f];
        }
        cA = cB; vA = vB; p = pn;
    }
    #pragma unroll
    for (int j = 0; j < J; j++) {
        int f = lane + 64 * j;
        if (f < F) out[(size_t)wid * outs + f] = acc[j];
    }
}

// ---------------- hidden: LDS-staged, y-split over 24-col chunks, uniform-scalar W1 ----------------
// grid (196, 2): block handles 256 nodes x 24 cols; K staged in 2 chunks of 50
__global__ __launch_bounds__(256) void k_hid(const float* __restrict__ xs, const float* __restrict__ W1,
                                             const float* __restrict__ b1, const float* __restrict__ gamma,
                                             const float* __restrict__ beta, const float* __restrict__ bn_mean,
                                             const float* __restrict__ bn_var, float* __restrict__ hid,
                                             int hs, int hoff, int h) {
    __shared__ float lt[50][257];   // transposed tile: lt[k][node], stride 257 -> conflict-free reads
    int tid = threadIdx.x;
    int n0 = blockIdx.x * 256;
    int y = blockIdx.y;             // 24-col chunk
    float acc[24];
    #pragma unroll
    for (int i = 0; i < 24; i++) acc[i] = 0.f;

    for (int ch = 0; ch < 2; ch++) {
        __syncthreads();
        for (int idx = tid; idx < 256 * 25; idx += 256) {
            int row = idx / 25, q = idx % 25;
            int n = n0 + row;
            if (n < NN) {
                float2 v = *(const float2*)(xs + (size_t)n * DD + 50 * ch + 2 * q);
                lt[2 * q + 0][row] = v.x;
                lt[2 * q + 1][row] = v.y;
            }
        }
        __syncthreads();
        if (n0 + tid < NN) {
            for (int kk = 0; kk < 50; kk++) {
                float xv = lt[kk][tid];
                int k = 50 * ch + kk;
                #pragma unroll
                for (int i = 0; i < 24; i++) {
                    int cc = 24 * y + i;
                    int r = cc / 16, j = cc % 16;
                    acc[i] += xv * W1[((size_t)(r * 4 + h) * DD + k) * HH + j];  // uniform -> s_load
                }
            }
        }
    }
    int n = n0 + tid;
    if (n < NN) {
        float* hr = hid + (size_t)n * hs + hoff;
        float o[24];
        #pragma unroll
        for (int i = 0; i < 24; i++) {
            int cc = 24 * y + i;
            int r = cc / 16, j = cc % 16;
            int ii = (r * 4 + h) * HH + j;
            float sc = gamma[ii] * rsqrtf(bn_var[ii] + 1e-5f);
            float sh = (b1[ii] - bn_mean[ii]) * sc + beta[ii];
            o[i] = fmaxf(acc[i] * sc + sh, 0.f);
        }
        #pragma unroll
        for (int q = 0; q < 6; q++)
            *(float4*)(hr + 24 * y + 4 * q) = make_float4(o[4 * q], o[4 * q + 1], o[4 * q + 2], o[4 * q + 3]);
    }
}

// ---------------- cell outputs: thread-per-(node,replica), uniform-scalar W2 ----------------
__global__ __launch_bounds__(256) void k_cellout(const float* __restrict__ hid, int hs, int hoff,
                                                 const float* __restrict__ W2, const float* __restrict__ b2v,
                                                 float* __restrict__ outcell, int h) {
    int n = blockIdx.x * 256 + threadIdx.x;
    int r = blockIdx.y;
    if (n >= NN) return;
    const float* hr = hid + (size_t)n * hs + hoff + r * HH;
    float x[HH];
    #pragma unroll
    for (int q = 0; q < HH / 4; q++) {
        float4 v = *(const float4*)(hr + 4 * q);
        x[4 * q + 0] = v.x; x[4 * q + 1] = v.y; x[4 * q + 2] = v.z; x[4 * q + 3] = v.w;
    }
    int cell = r * 4 + h;
    const float* wv = W2 + (size_t)cell * (HH * CC);
    float acc[CC];
    #pragma unroll
    for (int c = 0; c < CC; c++) acc[c] = b2v[cell * CC + c];   // uniform
    #pragma unroll
    for (int k = 0; k < HH; k++) {
        #pragma unroll
        for (int c = 0; c < CC; c++) acc[c] += x[k] * wv[k * CC + c];  // uniform -> s_load
    }
    float* o = outcell + (size_t)n * (NCELL * CC) + cell * CC;
    #pragma unroll
    for (int q = 0; q < CC / 4; q++)
        *(float4*)(o + 4 * q) = make_float4(acc[4 * q], acc[4 * q + 1], acc[4 * q + 2], acc[4 * q + 3]);
}

// ---------------- final stage 1: partial GEMM, K-split over grid.y ----------------
// grid (196, 4): block = 256 nodes, K-range 120 (chunks 32,32,32,24), LDS-staged transposed
__global__ __launch_bounds__(256) void k_fpart(const float* __restrict__ cell, const float* __restrict__ Wout,
                                               float* __restrict__ pout) {
    __shared__ float lt[32][257];   // lt[k][node]
    int tid = threadIdx.x;
    int n0 = blockIdx.x * 256;
    int y = blockIdx.y;
    int k0 = y * 120;
    float acc[CC];
    #pragma unroll
    for (int c = 0; c < CC; c++) acc[c] = 0.f;

    for (int c4 = 0; c4 < 4; c4++) {
        int CK = (c4 < 3) ? 32 : 24;
        int nf4 = CK / 4;            // 8 or 6 float4 per row
        int kbase = k0 + 32 * c4;
        __syncthreads();
        for (int idx = tid; idx < 256 * nf4; idx += 256) {
            int row = idx / nf4, q = idx % nf4;
            int n = n0 + row;
            if (n < NN) {
                float4 v = *(const float4*)(cell + (size_t)n * (NCELL * CC) + kbase + 4 * q);
                lt[4 * q + 0][row] = v.x;
                lt[4 * q + 1][row] = v.y;
                lt[4 * q + 2][row] = v.z;
                lt[4 * q + 3][row] = v.w;
            }
        }
        __syncthreads();
        if (n0 + tid < NN) {
            for (int kk = 0; kk < CK; kk++) {
                float xv = fmaxf(lt[kk][tid], 0.f);            // relu at use
                const float* wr = Wout + (size_t)(kbase + kk) * CC;
                #pragma unroll
                for (int c = 0; c < CC; c++) acc[c] += xv * wr[c];   // uniform -> s_load
            }
        }
    }
    int n = n0 + tid;
    if (n < NN) {
        float* o = pout + ((size_t)y * NN + n) * CC;
        #pragma unroll
        for (int q = 0; q < CC / 4; q++)
            *(float4*)(o + 4 * q) = make_float4(acc[4 * q], acc[4 * q + 1], acc[4 * q + 2], acc[4 * q + 3]);
    }
}

// ---------------- final stage 2: reduce 4 partials + bias (fully coalesced) ----------------
__global__ __launch_bounds__(256) void k_fred(const float* __restrict__ pout, const float* __restrict__ bout,
                                              float* __restrict__ out) {
    int idx = blockIdx.x * 256 + threadIdx.x;      // float4 index
    if (idx >= NN * CC / 4) return;
    const float4* p0 = (const float4*)pout;
    const float4* p1 = (const float4*)(pout + (size_t)1 * NN * CC);
    const float4* p2 = (const float4*)(pout + (size_t)2 * NN * CC);
    const float4* p3 = (const float4*)(pout + (size_t)3 * NN * CC);
    float4 a = p0[idx], b = p1[idx], c = p2[idx], d = p3[idx];
    int c0 = (idx * 4) % CC;
    float4 r;
    r.x = a.x + b.x + c.x + d.x + bout[c0 + 0];
    r.y = a.y + b.y + c.y + d.y + bout[c0 + 1];
    r.z = a.z + b.z + c.z + d.z + bout[c0 + 2];
    r.w = a.w + b.w + c.w + d.w + bout[c0 + 3];
    ((float4*)out)[idx] = r;
}

// ---------------- host ----------------

extern "C" void kernel_launch(void* const* d_in, const int* in_sizes, int n_in,
                              void* d_out, int out_size, void* d_ws, size_t ws_size,
                              hipStream_t stream) {
    const float* x       = (const float*)d_in[0];
    const int*   er      = (const int*)d_in[1];
    const int*   ec      = (const int*)d_in[2];
    const float* W1      = (const float*)d_in[3];
    const float* b1      = (const float*)d_in[4];
    const float* gamma   = (const float*)d_in[5];
    const float* beta    = (const float*)d_in[6];
    const float* bn_mean = (const float*)d_in[7];
    const float* bn_var  = (const float*)d_in[8];
    const float* W2      = (const float*)d_in[9];
    const float* b2v     = (const float*)d_in[10];
    const float* Wout    = (const float*)d_in[11];
    const float* bout    = (const float*)d_in[12];

    float* out     = (float*)d_out;               // [N, C] f32
    float* outcell = out + (size_t)NN * CC;       // [N, NC, C] f32

    char* w = (char*)d_ws;
    auto alloc = [&](size_t bytes) {
        void* p = (void*)w;
        w += (bytes + 255) & ~(size_t)255;
        return p;
    };
    int*   cnt    = (int*)alloc((size_t)NN * 4);
    int*   rp     = (int*)alloc((size_t)(NN + 1) * 4);
    int*   cursor = (int*)alloc((size_t)NN * 4);
    float* dinv   = (float*)alloc((size_t)NN * 4);
    int*   bsum   = (int*)alloc((size_t)(NB_SCAN + 1) * 4);
    int*   ci     = (int*)alloc((size_t)EE * 4);
    float* cv     = (float*)alloc((size_t)EE * 4);
    float* xsA    = (float*)alloc((size_t)NN * DD * 4);   // 20MB
    float* xsB    = (float*)alloc((size_t)NN * DD * 4);   // 20MB (contiguous after xsA)
    float* hid3   = (float*)alloc((size_t)NN * 144 * 4);  // 28.8MB
    // overlays (dead-region reuse, stream-ordered):
    float* S1   = xsA;    // [N,144] after xs arena dead
    float* S2   = hid3;   // [N,96]  after hid3 dead
    float* S3   = xsA;    // [N,48]  after S1 dead
    float* pout = xsA;    // [4][N,40] = 32MB after S3 consumed (xsA+xsB contiguous 40MB)

    hipMemsetAsync(cnt, 0, (size_t)NN * 4, stream);

    int gE = (EE + 255) / 256;
    int gN = (NN + 255) / 256;
    int gW = (NN + 3) / 4;   // spmm: wave per row

    k_hist<<<gE, 256, 0, stream>>>(er, cnt);
    k_dinv<<<gN, 256, 0, stream>>>(cnt, dinv);
    k_scan1<<<NB_SCAN, 1024, 0, stream>>>(cnt, rp, bsum);
    k_scan2<<<1, 64, 0, stream>>>(bsum);
    k_scan3<<<gN, 256, 0, stream>>>(rp, cursor, bsum);
    k_fill<<<gE, 256, 0, stream>>>(er, ec, dinv, cursor, ci, cv);

    k_norm<<<gW, 256, 0, stream>>>(x, xsA);

    // h=0
    k_hid<<<dim3(gN, 2), 256, 0, stream>>>(xsA, W1, b1, gamma, beta, bn_mean, bn_var, hid3, 144, 0, 0);
    k_cellout<<<dim3(gN, 3), 256, 0, stream>>>(hid3, 144, 0, W2, b2v, outcell, 0);

    k_spmm<DD><<<gW, 256, 0, stream>>>(rp, ci, cv, dinv, xsA, DD, 0, xsB, DD);   // xs1
    k_hid<<<dim3(gN, 2), 256, 0, stream>>>(xsB, W1, b1, gamma, beta, bn_mean, bn_var, hid3, 144, 0, 1);
    k_spmm<DD><<<gW, 256, 0, stream>>>(rp, ci, cv, dinv, xsB, DD, 0, xsA, DD);   // xs2
    k_hid<<<dim3(gN, 2), 256, 0, stream>>>(xsA, W1, b1, gamma, beta, bn_mean, bn_var, hid3, 144, 48, 2);
    k_spmm<DD><<<gW, 256, 0, stream>>>(rp, ci, cv, dinv, xsA, DD, 0, xsB, DD);   // xs3
    k_hid<<<dim3(gN, 2), 256, 0, stream>>>(xsB, W1, b1, gamma, beta, bn_mean, bn_var, hid3, 144, 96, 3);

    // batched hidden SpMM chains (xs arena dead from here)
    k_spmm<144><<<gW, 256, 0, stream>>>(rp, ci, cv, dinv, hid3, 144, 0, S1, 144);
    k_cellout<<<dim3(gN, 3), 256, 0, stream>>>(S1, 144, 0, W2, b2v, outcell, 1);
    k_spmm<96><<<gW, 256, 0, stream>>>(rp, ci, cv, dinv, S1, 144, 48, S2, 96);   // hid3 dead
    k_cellout<<<dim3(gN, 3), 256, 0, stream>>>(S2, 96, 0, W2, b2v, outcell, 2);
    k_spmm<48><<<gW, 256, 0, stream>>>(rp, ci, cv, dinv, S2, 96, 48, S3, 48);    // S1 dead
    k_cellout<<<dim3(gN, 3), 256, 0, stream>>>(S3, 48, 0, W2, b2v, outcell, 3);

    // final GEMM: K-split partials (pout overlays xs arena) + reduce
    k_fpart<<<dim3(gN, 4), 256, 0, stream>>>(outcell, Wout, pout);
    k_fred<<<(NN * CC / 4 + 255) / 256, 256, 0, stream>>>(pout, bout, out);
}

// Round 6
// 704.739 us; speedup vs baseline: 1.8202x; 1.8202x over previous
//
#include <hip/hip_runtime.h>
#include <hip/hip_bf16.h>

#define NN 50000
#define EE 800000
#define DD 100
#define HH 16
#define CC 40
#define NCELL 12
#define NB_SCAN 49   // ceil(50000/1024)

typedef __hip_bfloat162 bf2;

__device__ __forceinline__ float2 b2f2(bf2 v) { return __bfloat1622float2(v); }
__device__ __forceinline__ bf2 f22b2(float f0, float f1) {
    float2 t; t.x = f0; t.y = f1;
    return __float22bfloat162_rn(t);
}

// ---------------- graph preprocessing ----------------

__global__ __launch_bounds__(256) void k_hist(const int* __restrict__ er, int* __restrict__ cnt) {
    int e = blockIdx.x * 256 + threadIdx.x;
    if (e < EE) atomicAdd(&cnt[er[e]], 1);
}

__global__ __launch_bounds__(256) void k_dinv(const int* __restrict__ cnt, float* __restrict__ dinv) {
    int i = blockIdx.x * 256 + threadIdx.x;
    if (i < NN) dinv[i] = rsqrtf((float)(cnt[i] + 1));   // +1 self loop
}

__global__ __launch_bounds__(1024) void k_scan1(const int* __restrict__ cnt, int* __restrict__ rp,
                                                int* __restrict__ bsum) {
    __shared__ int lds[1024];
    int t = threadIdx.x, i = blockIdx.x * 1024 + t;
    int v = (i < NN) ? cnt[i] : 0;
    lds[t] = v;
    __syncthreads();
    #pragma unroll
    for (int off = 1; off < 1024; off <<= 1) {
        int x = lds[t];
        int y = (t >= off) ? lds[t - off] : 0;
        __syncthreads();
        lds[t] = x + y;
        __syncthreads();
    }
    if (i < NN) rp[i] = lds[t] - v;
    if (t == 1023) bsum[blockIdx.x] = lds[1023];
}

__global__ __launch_bounds__(64) void k_scan2(int* __restrict__ bsum) {
    int t = threadIdx.x;
    int orig = (t < NB_SCAN) ? bsum[t] : 0;
    int v = orig;
    #pragma unroll
    for (int off = 1; off < 64; off <<= 1) {
        int y = __shfl_up(v, off);
        if (t >= off) v += y;
    }
    if (t < NB_SCAN) bsum[t] = v - orig;
    if (t == NB_SCAN - 1) bsum[NB_SCAN] = v;
}

__global__ __launch_bounds__(256) void k_scan3(int* __restrict__ rp, int* __restrict__ cursor,
                                               const int* __restrict__ bsum) {
    int i = blockIdx.x * 256 + threadIdx.x;
    if (i < NN) {
        int v = rp[i] + bsum[i >> 10];
        rp[i] = v;
        cursor[i] = v;
    }
    if (i == 0) rp[NN] = bsum[NB_SCAN];
}

__global__ __launch_bounds__(256) void k_fill(const int* __restrict__ er, const int* __restrict__ ec,
                                              const float* __restrict__ dinv, int* __restrict__ cursor,
                                              int* __restrict__ ci, float* __restrict__ cv) {
    int e = blockIdx.x * 256 + threadIdx.x;
    if (e >= EE) return;
    int r = er[e], c = ec[e];
    int p = atomicAdd(&cursor[r], 1);
    ci[p] = c;
    cv[p] = dinv[r] * dinv[c];
}

// ---------------- projection: P[n, h*48 + r*16 + j] = (xn @ W1 * sc), bf16 ----------------
// norm fused: P_row = (x_row W1 Sc) / max(||x_row||,1e-12). block 256 = 64 nodes x 4 h-groups.
__global__ __launch_bounds__(256) void k_proj(const float* __restrict__ x, const float* __restrict__ W1,
                                              const float* __restrict__ gamma, const float* __restrict__ bn_var,
                                              bf2* __restrict__ P) {
    __shared__ float lt[DD][65];
    __shared__ float psum[4][64];
    __shared__ float ninv[64];
    int tid = threadIdx.x;
    int n0 = blockIdx.x * 64;
    int node_l = tid & 63;
    int g = tid >> 6;              // wave-uniform h

    // stage 64 x 100
    for (int idx = tid; idx < 64 * 25; idx += 256) {
        int nl = idx / 25, q = idx % 25;
        int n = n0 + nl;
        float4 v = (n < NN) ? *(const float4*)(x + (size_t)n * DD + 4 * q)
                            : make_float4(0.f, 0.f, 0.f, 0.f);
        lt[4 * q + 0][nl] = v.x;
        lt[4 * q + 1][nl] = v.y;
        lt[4 * q + 2][nl] = v.z;
        lt[4 * q + 3][nl] = v.w;
    }
    __syncthreads();
    // row norms
    {
        float s = 0.f;
        for (int k = 25 * g; k < 25 * g + 25; k++) {
            float v = lt[k][node_l];
            s += v * v;
        }
        psum[g][node_l] = s;
    }
    __syncthreads();
    if (tid < 64) {
        float ss = psum[0][tid] + psum[1][tid] + psum[2][tid] + psum[3][tid];
        ninv[tid] = 1.f / fmaxf(sqrtf(ss), 1e-12f);
    }
    __syncthreads();

    float acc[48];
    #pragma unroll
    for (int i = 0; i < 48; i++) acc[i] = 0.f;
    for (int k = 0; k < DD; k++) {
        float xv = lt[k][node_l];
        #pragma unroll
        for (int i = 0; i < 48; i++) {
            // cell = (i/16)*4 + g, col j = i%16
            acc[i] += xv * W1[(size_t)(((i / 16) * 4 + g) * DD + k) * HH + (i % 16)];
        }
    }
    int n = n0 + node_l;
    if (n < NN) {
        float f = ninv[node_l];
        bf2* pr = P + (size_t)n * 96 + g * 24;
        #pragma unroll
        for (int m = 0; m < 24; m++) {
            int i0 = 2 * m, i1 = 2 * m + 1;
            int c0 = ((i0 / 16) * 4 + g) * HH + (i0 % 16);
            int c1 = ((i1 / 16) * 4 + g) * HH + (i1 % 16);
            float s0 = gamma[c0] * rsqrtf(bn_var[c0] + 1e-5f);
            float s1 = gamma[c1] * rsqrtf(bn_var[c1] + 1e-5f);
            pr[m] = f22b2(acc[i0] * s0 * f, acc[i1] * s1 * f);
        }
    }
}

// ---------------- SpMM bf16: out = (D^-1/2 (A+I) D^-1/2) @ in ----------------
// NU = row width in bf162 units; RPW = rows per wave (1 or 2). ins/outs/ioff in bf162 units.
template <int NU, int RPW>
__global__ __launch_bounds__(256) void k_spmm(const int* __restrict__ rp, const int* __restrict__ ci,
                                              const float* __restrict__ cv, const float* __restrict__ dinv,
                                              const bf2* __restrict__ in, int ins, int ioff,
                                              bf2* __restrict__ out, int outs) {
    constexpr int LPR = (RPW == 1) ? 64 : 32;     // lanes per row
    constexpr int J = (NU + LPR - 1) / LPR;
    int gw = (blockIdx.x * 256 + threadIdx.x) >> 6;
    int lane = threadIdx.x & 63;
    int sub = (RPW == 2) ? (lane >> 5) : 0;
    int su = (RPW == 2) ? (lane & 31) : lane;
    int row = gw * RPW + sub;
    if (row >= NN) return;
    const bf2* ib = in + ioff;

    float d = dinv[row];
    float sw = d * d;
    float2 acc[J];
    {
        size_t b = (size_t)row * ins;
        #pragma unroll
        for (int j = 0; j < J; j++) {
            int u = su + LPR * j;
            if (u < NU) {
                float2 f = b2f2(ib[b + u]);
                acc[j].x = sw * f.x; acc[j].y = sw * f.y;
            } else { acc[j].x = 0.f; acc[j].y = 0.f; }
        }
    }
    int s = rp[row], e = rp[row + 1];
    int p = s;
    int e4 = s + ((e - s) & ~3);
    while (p < e4) {
        int c0 = ci[p], c1 = ci[p + 1], c2 = ci[p + 2], c3 = ci[p + 3];
        float v0 = cv[p], v1 = cv[p + 1], v2 = cv[p + 2], v3 = cv[p + 3];
        bf2 r0[J], r1[J], r2[J], r3[J];
        size_t b0 = (size_t)c0 * ins, b1 = (size_t)c1 * ins, b2 = (size_t)c2 * ins, b3 = (size_t)c3 * ins;
        #pragma unroll
        for (int j = 0; j < J; j++) {
            int u = su + LPR * j;
            if (u < NU) {
                r0[j] = ib[b0 + u]; r1[j] = ib[b1 + u];
                r2[j] = ib[b2 + u]; r3[j] = ib[b3 + u];
            }
        }
        #pragma unroll
        for (int j = 0; j < J; j++) {
            int u = su + LPR * j;
            if (u < NU) {
                float2 f0 = b2f2(r0[j]), f1 = b2f2(r1[j]), f2 = b2f2(r2[j]), f3 = b2f2(r3[j]);
                acc[j].x += v0 * f0.x + v1 * f1.x + v2 * f2.x + v3 * f3.x;
                acc[j].y += v0 * f0.y + v1 * f1.y + v2 * f2.y + v3 * f3.y;
            }
        }
        p += 4;
    }
    while (p < e) {
        int c = ci[p];
        float v = cv[p];
        size_t b = (size_t)c * ins;
        #pragma unroll
        for (int j = 0; j < J; j++) {
            int u = su + LPR * j;
            if (u < NU) {
                float2 f = b2f2(ib[b + u]);
                acc[j].x += v * f.x; acc[j].y += v * f.y;
            }
        }
        p++;
    }
    size_t ob = (size_t)row * outs;
    #pragma unroll
    for (int j = 0; j < J; j++) {
        int u = su + LPR * j;
        if (u < NU) out[ob + u] = f22b2(acc[j].x, acc[j].y);
    }
}

// ---------------- BN shift + ReLU: H0[N,48] from P, H123[N,144] from R1/R2/R3 ----------------
__global__ __launch_bounds__(256) void k_bnrelu(const bf2* __restrict__ P, const bf2* __restrict__ R1,
                                                const bf2* __restrict__ R2, const bf2* __restrict__ R3,
                                                const float* __restrict__ b1, const float* __restrict__ gamma,
                                                const float* __restrict__ beta, const float* __restrict__ bn_mean,
                                                const float* __restrict__ bn_var,
                                                bf2* __restrict__ H0, bf2* __restrict__ H123) {
    int idx = blockIdx.x * 256 + threadIdx.x;
    if (idx >= NN * 96) return;
    int n = idx / 96, u = idx % 96;
    int h, su;
    bf2 v;
    if (u < 24) { h = 0; su = u; v = P[(size_t)n * 96 + su]; }
    else {
        int uu = u - 24;
        h = uu / 24 + 1; su = uu % 24;
        if (h == 1)      v = R1[(size_t)n * 72 + su];
        else if (h == 2) v = R2[(size_t)n * 48 + su];
        else             v = R3[(size_t)n * 24 + su];
    }
    int c0 = 2 * su;                       // within 48-block
    int cell = (c0 / 16) * 4 + h;
    int j0 = c0 % 16;
    int i0 = cell * HH + j0, i1 = i0 + 1;  // pairs never cross r boundary
    float s0 = gamma[i0] * rsqrtf(bn_var[i0] + 1e-5f);
    float s1 = gamma[i1] * rsqrtf(bn_var[i1] + 1e-5f);
    float sh0 = (b1[i0] - bn_mean[i0]) * s0 + beta[i0];
    float sh1 = (b1[i1] - bn_mean[i1]) * s1 + beta[i1];
    float2 f = b2f2(v);
    bf2 o = f22b2(fmaxf(f.x + sh0, 0.f), fmaxf(f.y + sh1, 0.f));
    if (u < 24) H0[(size_t)n * 24 + u] = o;
    else        H123[(size_t)n * 72 + (u - 24)] = o;
}

// ---------------- cell outputs: weight-in-register, wave-pair per node ----------------
// block 128 (2 waves = 1 node unit), grid NUNITS; outcell[n, cell*40+c] coalesced float4 writes
#define NUNITS 1024
__global__ __launch_bounds__(128) void k_cellout(const bf2* __restrict__ H0, const bf2* __restrict__ U1,
                                                 const bf2* __restrict__ U2, const bf2* __restrict__ U3,
                                                 const float* __restrict__ W2, const float* __restrict__ b2v,
                                                 float* __restrict__ outcell) {
    __shared__ float row[2][200];
    int tid = threadIdx.x;
    int gid = tid;                    // 0..127, active < 120
    bool act = gid < 120;
    int cell = act ? gid / 10 : 0;
    int cc = act ? (4 * gid) % 40 : 0;
    int h = cell & 3, r = cell >> 2;
    float4 wreg[HH];
    float4 bias = make_float4(0.f, 0.f, 0.f, 0.f);
    if (act) {
        #pragma unroll
        for (int k = 0; k < HH; k++)
            wreg[k] = *(const float4*)(W2 + (size_t)cell * (HH * CC) + k * CC + cc);
        bias = *(const float4*)(b2v + cell * CC + cc);
    }
    int colbase = h * 48 + r * 16;

    const bf2* tabs[4] = {H0, U1, U2, U3};
    const int strides[4] = {24, 72, 48, 24};

    int iters = (NN + NUNITS - 1) / NUNITS;
    int n_cur = blockIdx.x;
    // prologue stage into buf 0
    if (tid < 96 && n_cur < NN) {
        int t4 = tid / 24, uu = tid % 24;
        float2 f = b2f2(tabs[t4][(size_t)n_cur * strides[t4] + uu]);
        row[0][t4 * 48 + 2 * uu] = f.x;
        row[0][t4 * 48 + 2 * uu + 1] = f.y;
    }
    __syncthreads();
    for (int it = 0; it < iters; it++) {
        int buf = it & 1;
        int n_next = n_cur + NUNITS;
        if (it + 1 < iters && tid < 96 && n_next < NN) {
            int t4 = tid / 24, uu = tid % 24;
            float2 f = b2f2(tabs[t4][(size_t)n_next * strides[t4] + uu]);
            row[buf ^ 1][t4 * 48 + 2 * uu] = f.x;
            row[buf ^ 1][t4 * 48 + 2 * uu + 1] = f.y;
        }
        if (act && n_cur < NN) {
            float4 acc = bias;
            #pragma unroll
            for (int k = 0; k < HH; k++) {
                float xv = row[buf][colbase + k];
                acc.x += xv * wreg[k].x;
                acc.y += xv * wreg[k].y;
                acc.z += xv * wreg[k].z;
                acc.w += xv * wreg[k].w;
            }
            *(float4*)(outcell + (size_t)n_cur * (NCELL * CC) + 4 * gid) = acc;
        }
        __syncthreads();
        n_cur = n_next;
    }
}

// ---------------- final: block = 64 nodes x 4 groups x 10 cols, K-chunked 5x96 ----------------
__global__ __launch_bounds__(256) void k_final(const float* __restrict__ cell, const float* __restrict__ Wout,
                                               const float* __restrict__ bout, float* __restrict__ out) {
    __shared__ float lt[96][65];
    int tid = threadIdx.x;
    int n0 = blockIdx.x * 64;
    int node_l = tid & 63;
    int g = tid >> 6;
    float acc[10];
    #pragma unroll
    for (int i = 0; i < 10; i++) acc[i] = bout[g * 10 + i];

    for (int ch = 0; ch < 5; ch++) {
        __syncthreads();
        for (int idx = tid; idx < 64 * 24; idx += 256) {
            int n = idx / 24, q = idx % 24;
            int nn = n0 + n;
            float4 v = (nn < NN) ? *(const float4*)(cell + (size_t)nn * (NCELL * CC) + ch * 96 + 4 * q)
                                 : make_float4(0.f, 0.f, 0.f, 0.f);
            lt[4 * q + 0][n] = v.x;
            lt[4 * q + 1][n] = v.y;
            lt[4 * q + 2][n] = v.z;
            lt[4 * q + 3][n] = v.w;
        }
        __syncthreads();
        for (int k = 0; k < 96; k++) {
            float xv = fmaxf(lt[k][node_l], 0.f);
            int kk = ch * 96 + k;
            #pragma unroll
            for (int i = 0; i < 10; i++)
                acc[i] += xv * Wout[(size_t)kk * CC + g * 10 + i];
        }
    }
    int n = n0 + node_l;
    if (n < NN) {
        float* o = out + (size_t)n * CC + g * 10;
        #pragma unroll
        for (int i = 0; i < 10; i++) o[i] = acc[i];
    }
}

// ---------------- host ----------------

extern "C" void kernel_launch(void* const* d_in, const int* in_sizes, int n_in,
                              void* d_out, int out_size, void* d_ws, size_t ws_size,
                              hipStream_t stream) {
    const float* x       = (const float*)d_in[0];
    const int*   er      = (const int*)d_in[1];
    const int*   ec      = (const int*)d_in[2];
    const float* W1      = (const float*)d_in[3];
    const float* b1      = (const float*)d_in[4];
    const float* gamma   = (const float*)d_in[5];
    const float* beta    = (const float*)d_in[6];
    const float* bn_mean = (const float*)d_in[7];
    const float* bn_var  = (const float*)d_in[8];
    const float* W2      = (const float*)d_in[9];
    const float* b2v     = (const float*)d_in[10];
    const float* Wout    = (const float*)d_in[11];
    const float* bout    = (const float*)d_in[12];

    float* out     = (float*)d_out;               // [N, C] f32
    float* outcell = out + (size_t)NN * CC;       // [N, NC, C] f32

    char* w = (char*)d_ws;
    auto alloc = [&](size_t bytes) {
        void* p = (void*)w;
        w += (bytes + 255) & ~(size_t)255;
        return p;
    };
    int*   cnt    = (int*)alloc((size_t)NN * 4);
    int*   rp     = (int*)alloc((size_t)(NN + 1) * 4);
    int*   cursor = (int*)alloc((size_t)NN * 4);
    float* dinv   = (float*)alloc((size_t)NN * 4);
    int*   bsum   = (int*)alloc((size_t)(NB_SCAN + 1) * 4);
    int*   ci     = (int*)alloc((size_t)EE * 4);
    float* cv     = (float*)alloc((size_t)EE * 4);
    bf2*   P      = (bf2*)alloc((size_t)NN * 96 * 4);   // [N,192] bf16
    bf2*   R1     = (bf2*)alloc((size_t)NN * 72 * 4);   // [N,144]
    bf2*   R2     = (bf2*)alloc((size_t)NN * 48 * 4);   // [N,96]
    bf2*   R3     = (bf2*)alloc((size_t)NN * 24 * 4);   // [N,48]
    bf2*   H0     = (bf2*)alloc((size_t)NN * 24 * 4);   // [N,48]
    bf2*   H123   = (bf2*)alloc((size_t)NN * 72 * 4);   // [N,144]
    bf2*   U1     = (bf2*)alloc((size_t)NN * 72 * 4);   // [N,144]
    bf2*   U2     = (bf2*)alloc((size_t)NN * 48 * 4);   // [N,96]
    bf2*   U3     = (bf2*)alloc((size_t)NN * 24 * 4);   // [N,48]

    hipMemsetAsync(cnt, 0, (size_t)NN * 4, stream);

    int gE = (EE + 255) / 256;
    int gN = (NN + 255) / 256;

    k_hist<<<gE, 256, 0, stream>>>(er, cnt);
    k_dinv<<<gN, 256, 0, stream>>>(cnt, dinv);
    k_scan1<<<NB_SCAN, 1024, 0, stream>>>(cnt, rp, bsum);
    k_scan2<<<1, 64, 0, stream>>>(bsum);
    k_scan3<<<gN, 256, 0, stream>>>(rp, cursor, bsum);
    k_fill<<<gE, 256, 0, stream>>>(er, ec, dinv, cursor, ci, cv);

    int g64 = (NN + 63) / 64;      // 64-node blocks
    k_proj<<<g64, 256, 0, stream>>>(x, W1, gamma, bn_var, P);

    int gW1 = (NN + 3) / 4;        // RPW=1: 4 rows/block
    int gW2 = (NN + 7) / 8;        // RPW=2: 8 rows/block
    // inner chain: R1 = A@P[:,48:192]; R2 = A@R1[:,48:144]; R3 = A@R2[:,48:96]
    k_spmm<72, 1><<<gW1, 256, 0, stream>>>(rp, ci, cv, dinv, P, 96, 24, R1, 72);
    k_spmm<48, 1><<<gW1, 256, 0, stream>>>(rp, ci, cv, dinv, R1, 72, 24, R2, 48);
    k_spmm<24, 2><<<gW2, 256, 0, stream>>>(rp, ci, cv, dinv, R2, 48, 24, R3, 24);

    k_bnrelu<<<(NN * 96 + 255) / 256, 256, 0, stream>>>(P, R1, R2, R3, b1, gamma, beta, bn_mean, bn_var, H0, H123);

    // outer chain: U1 = A@H123; U2 = A@U1[:,48:144]; U3 = A@U2[:,48:96]
    k_spmm<72, 1><<<gW1, 256, 0, stream>>>(rp, ci, cv, dinv, H123, 72, 0, U1, 72);
    k_spmm<48, 1><<<gW1, 256, 0, stream>>>(rp, ci, cv, dinv, U1, 72, 24, U2, 48);
    k_spmm<24, 2><<<gW2, 256, 0, stream>>>(rp, ci, cv, dinv, U2, 48, 24, U3, 24);

    k_cellout<<<NUNITS, 128, 0, stream>>>(H0, U1, U2, U3, W2, b2v, outcell);
    k_final<<<g64, 256, 0, stream>>>(outcell, Wout, bout, out);
}

// Round 7
// 551.934 us; speedup vs baseline: 2.3241x; 1.2769x over previous
//
#include <hip/hip_runtime.h>
#include <hip/hip_bf16.h>

#define NN 50000
#define EE 800000
#define DD 100
#define HH 16
#define CC 40
#define NCELL 12
#define NB_SCAN 49   // ceil(50000/1024)

typedef __hip_bfloat162 bf2;
typedef short bf16x8 __attribute__((ext_vector_type(8)));
typedef float f32x4 __attribute__((ext_vector_type(4)));

__device__ __forceinline__ float2 b2f2(bf2 v) { return __bfloat1622float2(v); }
__device__ __forceinline__ bf2 f22b2(float f0, float f1) {
    float2 t; t.x = f0; t.y = f1;
    return __float22bfloat162_rn(t);
}
__device__ __forceinline__ unsigned short f2b(float f) {
    __hip_bfloat16 h = __float2bfloat16(f);
    return *reinterpret_cast<unsigned short*>(&h);
}

// ---------------- graph preprocessing ----------------

__global__ __launch_bounds__(256) void k_hist(const int* __restrict__ er, int* __restrict__ cnt) {
    int e = blockIdx.x * 256 + threadIdx.x;
    if (e < EE) atomicAdd(&cnt[er[e]], 1);
}

__global__ __launch_bounds__(256) void k_dinv(const int* __restrict__ cnt, float* __restrict__ dinv) {
    int i = blockIdx.x * 256 + threadIdx.x;
    if (i < NN) dinv[i] = rsqrtf((float)(cnt[i] + 1));   // +1 self loop
}

__global__ __launch_bounds__(1024) void k_scan1(const int* __restrict__ cnt, int* __restrict__ rp,
                                                int* __restrict__ bsum) {
    __shared__ int lds[1024];
    int t = threadIdx.x, i = blockIdx.x * 1024 + t;
    int v = (i < NN) ? cnt[i] : 0;
    lds[t] = v;
    __syncthreads();
    #pragma unroll
    for (int off = 1; off < 1024; off <<= 1) {
        int x = lds[t];
        int y = (t >= off) ? lds[t - off] : 0;
        __syncthreads();
        lds[t] = x + y;
        __syncthreads();
    }
    if (i < NN) rp[i] = lds[t] - v;
    if (t == 1023) bsum[blockIdx.x] = lds[1023];
}

__global__ __launch_bounds__(64) void k_scan2(int* __restrict__ bsum) {
    int t = threadIdx.x;
    int orig = (t < NB_SCAN) ? bsum[t] : 0;
    int v = orig;
    #pragma unroll
    for (int off = 1; off < 64; off <<= 1) {
        int y = __shfl_up(v, off);
        if (t >= off) v += y;
    }
    if (t < NB_SCAN) bsum[t] = v - orig;
    if (t == NB_SCAN - 1) bsum[NB_SCAN] = v;
}

__global__ __launch_bounds__(256) void k_scan3(int* __restrict__ rp, int* __restrict__ cursor,
                                               const int* __restrict__ bsum) {
    int i = blockIdx.x * 256 + threadIdx.x;
    if (i < NN) {
        int v = rp[i] + bsum[i >> 10];
        rp[i] = v;
        cursor[i] = v;
    }
    if (i == 0) rp[NN] = bsum[NB_SCAN];
}

__global__ __launch_bounds__(256) void k_fill(const int* __restrict__ er, const int* __restrict__ ec,
                                              const float* __restrict__ dinv, int* __restrict__ cursor,
                                              int* __restrict__ ci, float* __restrict__ cv) {
    int e = blockIdx.x * 256 + threadIdx.x;
    if (e >= EE) return;
    int r = er[e], c = ec[e];
    int p = atomicAdd(&cursor[r], 1);
    ci[p] = c;
    cv[p] = dinv[r] * dinv[c];
}

// ---------------- projection: P[n, h*48 + r*16 + j] = (xn @ W1 * sc), bf16 ----------------
__global__ __launch_bounds__(256) void k_proj(const float* __restrict__ x, const float* __restrict__ W1,
                                              const float* __restrict__ gamma, const float* __restrict__ bn_var,
                                              bf2* __restrict__ P) {
    __shared__ float lt[DD][65];
    __shared__ float psum[4][64];
    __shared__ float ninv[64];
    int tid = threadIdx.x;
    int n0 = blockIdx.x * 64;
    int node_l = tid & 63;
    int g = tid >> 6;              // wave-uniform h

    for (int idx = tid; idx < 64 * 25; idx += 256) {
        int nl = idx / 25, q = idx % 25;
        int n = n0 + nl;
        float4 v = (n < NN) ? *(const float4*)(x + (size_t)n * DD + 4 * q)
                            : make_float4(0.f, 0.f, 0.f, 0.f);
        lt[4 * q + 0][nl] = v.x;
        lt[4 * q + 1][nl] = v.y;
        lt[4 * q + 2][nl] = v.z;
        lt[4 * q + 3][nl] = v.w;
    }
    __syncthreads();
    {
        float s = 0.f;
        for (int k = 25 * g; k < 25 * g + 25; k++) {
            float v = lt[k][node_l];
            s += v * v;
        }
        psum[g][node_l] = s;
    }
    __syncthreads();
    if (tid < 64) {
        float ss = psum[0][tid] + psum[1][tid] + psum[2][tid] + psum[3][tid];
        ninv[tid] = 1.f / fmaxf(sqrtf(ss), 1e-12f);
    }
    __syncthreads();

    float acc[48];
    #pragma unroll
    for (int i = 0; i < 48; i++) acc[i] = 0.f;
    for (int k = 0; k < DD; k++) {
        float xv = lt[k][node_l];
        #pragma unroll
        for (int i = 0; i < 48; i++) {
            acc[i] += xv * W1[(size_t)(((i / 16) * 4 + g) * DD + k) * HH + (i % 16)];
        }
    }
    int n = n0 + node_l;
    if (n < NN) {
        float f = ninv[node_l];
        bf2* pr = P + (size_t)n * 96 + g * 24;
        #pragma unroll
        for (int m = 0; m < 24; m++) {
            int i0 = 2 * m, i1 = 2 * m + 1;
            int c0 = ((i0 / 16) * 4 + g) * HH + (i0 % 16);
            int c1 = ((i1 / 16) * 4 + g) * HH + (i1 % 16);
            float s0 = gamma[c0] * rsqrtf(bn_var[c0] + 1e-5f);
            float s1 = gamma[c1] * rsqrtf(bn_var[c1] + 1e-5f);
            pr[m] = f22b2(acc[i0] * s0 * f, acc[i1] * s1 * f);
        }
    }
}

// ---------------- SpMM bf16 ----------------
template <int NU, int RPW>
__global__ __launch_bounds__(256) void k_spmm(const int* __restrict__ rp, const int* __restrict__ ci,
                                              const float* __restrict__ cv, const float* __restrict__ dinv,
                                              const bf2* __restrict__ in, int ins, int ioff,
                                              bf2* __restrict__ out, int outs) {
    constexpr int LPR = (RPW == 1) ? 64 : 32;
    constexpr int J = (NU + LPR - 1) / LPR;
    int gw = (blockIdx.x * 256 + threadIdx.x) >> 6;
    int lane = threadIdx.x & 63;
    int sub = (RPW == 2) ? (lane >> 5) : 0;
    int su = (RPW == 2) ? (lane & 31) : lane;
    int row = gw * RPW + sub;
    if (row >= NN) return;
    const bf2* ib = in + ioff;

    float d = dinv[row];
    float sw = d * d;
    float2 acc[J];
    {
        size_t b = (size_t)row * ins;
        #pragma unroll
        for (int j = 0; j < J; j++) {
            int u = su + LPR * j;
            if (u < NU) {
                float2 f = b2f2(ib[b + u]);
                acc[j].x = sw * f.x; acc[j].y = sw * f.y;
            } else { acc[j].x = 0.f; acc[j].y = 0.f; }
        }
    }
    int s = rp[row], e = rp[row + 1];
    int p = s;
    int e4 = s + ((e - s) & ~3);
    while (p < e4) {
        int c0 = ci[p], c1 = ci[p + 1], c2 = ci[p + 2], c3 = ci[p + 3];
        float v0 = cv[p], v1 = cv[p + 1], v2 = cv[p + 2], v3 = cv[p + 3];
        bf2 r0[J], r1[J], r2[J], r3[J];
        size_t b0 = (size_t)c0 * ins, b1 = (size_t)c1 * ins, b2 = (size_t)c2 * ins, b3 = (size_t)c3 * ins;
        #pragma unroll
        for (int j = 0; j < J; j++) {
            int u = su + LPR * j;
            if (u < NU) {
                r0[j] = ib[b0 + u]; r1[j] = ib[b1 + u];
                r2[j] = ib[b2 + u]; r3[j] = ib[b3 + u];
            }
        }
        #pragma unroll
        for (int j = 0; j < J; j++) {
            int u = su + LPR * j;
            if (u < NU) {
                float2 f0 = b2f2(r0[j]), f1 = b2f2(r1[j]), f2 = b2f2(r2[j]), f3 = b2f2(r3[j]);
                acc[j].x += v0 * f0.x + v1 * f1.x + v2 * f2.x + v3 * f3.x;
                acc[j].y += v0 * f0.y + v1 * f1.y + v2 * f2.y + v3 * f3.y;
            }
        }
        p += 4;
    }
    while (p < e) {
        int c = ci[p];
        float v = cv[p];
        size_t b = (size_t)c * ins;
        #pragma unroll
        for (int j = 0; j < J; j++) {
            int u = su + LPR * j;
            if (u < NU) {
                float2 f = b2f2(ib[b + u]);
                acc[j].x += v * f.x; acc[j].y += v * f.y;
            }
        }
        p++;
    }
    size_t ob = (size_t)row * outs;
    #pragma unroll
    for (int j = 0; j < J; j++) {
        int u = su + LPR * j;
        if (u < NU) out[ob + u] = f22b2(acc[j].x, acc[j].y);
    }
}

// ---------------- BN shift + ReLU ----------------
__global__ __launch_bounds__(256) void k_bnrelu(const bf2* __restrict__ P, const bf2* __restrict__ R1,
                                                const bf2* __restrict__ R2, const bf2* __restrict__ R3,
                                                const float* __restrict__ b1, const float* __restrict__ gamma,
                                                const float* __restrict__ beta, const float* __restrict__ bn_mean,
                                                const float* __restrict__ bn_var,
                                                bf2* __restrict__ H0, bf2* __restrict__ H123) {
    int idx = blockIdx.x * 256 + threadIdx.x;
    if (idx >= NN * 96) return;
    int n = idx / 96, u = idx % 96;
    int h, su;
    bf2 v;
    if (u < 24) { h = 0; su = u; v = P[(size_t)n * 96 + su]; }
    else {
        int uu = u - 24;
        h = uu / 24 + 1; su = uu % 24;
        if (h == 1)      v = R1[(size_t)n * 72 + su];
        else if (h == 2) v = R2[(size_t)n * 48 + su];
        else             v = R3[(size_t)n * 24 + su];
    }
    int c0 = 2 * su;
    int cell = (c0 / 16) * 4 + h;
    int j0 = c0 % 16;
    int i0 = cell * HH + j0, i1 = i0 + 1;
    float s0 = gamma[i0] * rsqrtf(bn_var[i0] + 1e-5f);
    float s1 = gamma[i1] * rsqrtf(bn_var[i1] + 1e-5f);
    float sh0 = (b1[i0] - bn_mean[i0]) * s0 + beta[i0];
    float sh1 = (b1[i1] - bn_mean[i1]) * s1 + beta[i1];
    float2 f = b2f2(v);
    bf2 o = f22b2(fmaxf(f.x + sh0, 0.f), fmaxf(f.y + sh1, 0.f));
    if (u < 24) H0[(size_t)n * 24 + u] = o;
    else        H123[(size_t)n * 72 + (u - 24)] = o;
}

// ---------------- cell outputs: weight-in-register, wave-pair per node ----------------
#define NUNITS 1024
__global__ __launch_bounds__(128) void k_cellout(const bf2* __restrict__ H0, const bf2* __restrict__ U1,
                                                 const bf2* __restrict__ U2, const bf2* __restrict__ U3,
                                                 const float* __restrict__ W2, const float* __restrict__ b2v,
                                                 float* __restrict__ outcell) {
    __shared__ float row[2][200];
    int tid = threadIdx.x;
    int gid = tid;
    bool act = gid < 120;
    int cell = act ? gid / 10 : 0;
    int cc = act ? (4 * gid) % 40 : 0;
    int h = cell & 3, r = cell >> 2;
    float4 wreg[HH];
    float4 bias = make_float4(0.f, 0.f, 0.f, 0.f);
    if (act) {
        #pragma unroll
        for (int k = 0; k < HH; k++)
            wreg[k] = *(const float4*)(W2 + (size_t)cell * (HH * CC) + k * CC + cc);
        bias = *(const float4*)(b2v + cell * CC + cc);
    }
    int colbase = h * 48 + r * 16;

    const bf2* tabs[4] = {H0, U1, U2, U3};
    const int strides[4] = {24, 72, 48, 24};

    int iters = (NN + NUNITS - 1) / NUNITS;
    int n_cur = blockIdx.x;
    if (tid < 96 && n_cur < NN) {
        int t4 = tid / 24, uu = tid % 24;
        float2 f = b2f2(tabs[t4][(size_t)n_cur * strides[t4] + uu]);
        row[0][t4 * 48 + 2 * uu] = f.x;
        row[0][t4 * 48 + 2 * uu + 1] = f.y;
    }
    __syncthreads();
    for (int it = 0; it < iters; it++) {
        int buf = it & 1;
        int n_next = n_cur + NUNITS;
        if (it + 1 < iters && tid < 96 && n_next < NN) {
            int t4 = tid / 24, uu = tid % 24;
            float2 f = b2f2(tabs[t4][(size_t)n_next * strides[t4] + uu]);
            row[buf ^ 1][t4 * 48 + 2 * uu] = f.x;
            row[buf ^ 1][t4 * 48 + 2 * uu + 1] = f.y;
        }
        if (act && n_cur < NN) {
            float4 acc = bias;
            #pragma unroll
            for (int k = 0; k < HH; k++) {
                float xv = row[buf][colbase + k];
                acc.x += xv * wreg[k].x;
                acc.y += xv * wreg[k].y;
                acc.z += xv * wreg[k].z;
                acc.w += xv * wreg[k].w;
            }
            *(float4*)(outcell + (size_t)n_cur * (NCELL * CC) + 4 * gid) = acc;
        }
        __syncthreads();
        n_cur = n_next;
    }
}

// ---------------- Wout pre-transpose: WoutT[48][480] bf16, zero-padded ----------------
__global__ __launch_bounds__(256) void k_wt(const float* __restrict__ Wout, unsigned short* __restrict__ WoutT) {
    int idx = blockIdx.x * 256 + threadIdx.x;
    if (idx >= 48 * 480) return;
    int c = idx / 480, k = idx % 480;
    float v = (c < CC) ? Wout[(size_t)k * CC + c] : 0.f;
    WoutT[idx] = f2b(v);
}

// ---------------- final: MFMA GEMM  out = relu(cell) @ Wout + bout ----------------
// block 256 = 4 waves; wave = 16-row strip x 48 cols (3 tiles) x K=480 (15 steps)
__global__ __launch_bounds__(256) void k_final_mfma(const float* __restrict__ cell,
                                                    const unsigned short* __restrict__ WoutT,
                                                    const float* __restrict__ bout, float* __restrict__ out) {
    int tid = threadIdx.x;
    int wid = tid >> 6, lane = tid & 63;
    int rowbase = blockIdx.x * 64 + wid * 16;
    int arow = rowbase + (lane & 15);
    int arow_c = (arow < NN) ? arow : NN - 1;     // clamp for loads; stores masked
    int kgrp = lane >> 4;                          // 0..3 -> k-subrange *8

    f32x4 acc0 = {0.f, 0.f, 0.f, 0.f};
    f32x4 acc1 = {0.f, 0.f, 0.f, 0.f};
    f32x4 acc2 = {0.f, 0.f, 0.f, 0.f};

    const float* arow_p = cell + (size_t)arow_c * (NCELL * CC);
    int bcol = lane & 15;

    for (int kt = 0; kt < 15; kt++) {
        int k0 = kt * 32 + kgrp * 8;
        // A fragment: relu(cell[arow][k0..k0+7]) -> bf16x8
        float4 va = *(const float4*)(arow_p + k0);
        float4 vb = *(const float4*)(arow_p + k0 + 4);
        bf16x8 afr;
        afr[0] = (short)f2b(fmaxf(va.x, 0.f));
        afr[1] = (short)f2b(fmaxf(va.y, 0.f));
        afr[2] = (short)f2b(fmaxf(va.z, 0.f));
        afr[3] = (short)f2b(fmaxf(va.w, 0.f));
        afr[4] = (short)f2b(fmaxf(vb.x, 0.f));
        afr[5] = (short)f2b(fmaxf(vb.y, 0.f));
        afr[6] = (short)f2b(fmaxf(vb.z, 0.f));
        afr[7] = (short)f2b(fmaxf(vb.w, 0.f));
        // B fragments: WoutT[colt*16 + bcol][k0..k0+7]
        bf16x8 bf0 = *(const bf16x8*)(WoutT + (size_t)(0 * 16 + bcol) * 480 + k0);
        bf16x8 bf1 = *(const bf16x8*)(WoutT + (size_t)(1 * 16 + bcol) * 480 + k0);
        bf16x8 bf2f = *(const bf16x8*)(WoutT + (size_t)(2 * 16 + bcol) * 480 + k0);
        acc0 = __builtin_amdgcn_mfma_f32_16x16x32_bf16(afr, bf0, acc0, 0, 0, 0);
        acc1 = __builtin_amdgcn_mfma_f32_16x16x32_bf16(afr, bf1, acc1, 0, 0, 0);
        acc2 = __builtin_amdgcn_mfma_f32_16x16x32_bf16(afr, bf2f, acc2, 0, 0, 0);
    }

    // D layout: col = lane&15, row = (lane>>4)*4 + reg
    int drow = rowbase + (lane >> 4) * 4;
    #pragma unroll
    for (int r = 0; r < 4; r++) {
        int grow = drow + r;
        if (grow < NN) {
            int c0 = 0 * 16 + (lane & 15);
            int c1 = 1 * 16 + (lane & 15);
            int c2 = 2 * 16 + (lane & 15);
            float* o = out + (size_t)grow * CC;
            o[c0] = acc0[r] + bout[c0];
            o[c1] = acc1[r] + bout[c1];
            if (c2 < CC) o[c2] = acc2[r] + bout[c2];
        }
    }
}

// ---------------- host ----------------

extern "C" void kernel_launch(void* const* d_in, const int* in_sizes, int n_in,
                              void* d_out, int out_size, void* d_ws, size_t ws_size,
                              hipStream_t stream) {
    const float* x       = (const float*)d_in[0];
    const int*   er      = (const int*)d_in[1];
    const int*   ec      = (const int*)d_in[2];
    const float* W1      = (const float*)d_in[3];
    const float* b1      = (const float*)d_in[4];
    const float* gamma   = (const float*)d_in[5];
    const float* beta    = (const float*)d_in[6];
    const float* bn_mean = (const float*)d_in[7];
    const float* bn_var  = (const float*)d_in[8];
    const float* W2      = (const float*)d_in[9];
    const float* b2v     = (const float*)d_in[10];
    const float* Wout    = (const float*)d_in[11];
    const float* bout    = (const float*)d_in[12];

    float* out     = (float*)d_out;               // [N, C] f32
    float* outcell = out + (size_t)NN * CC;       // [N, NC, C] f32

    char* w = (char*)d_ws;
    auto alloc = [&](size_t bytes) {
        void* p = (void*)w;
        w += (bytes + 255) & ~(size_t)255;
        return p;
    };
    int*   cnt    = (int*)alloc((size_t)NN * 4);
    int*   rp     = (int*)alloc((size_t)(NN + 1) * 4);
    int*   cursor = (int*)alloc((size_t)NN * 4);
    float* dinv   = (float*)alloc((size_t)NN * 4);
    int*   bsum   = (int*)alloc((size_t)(NB_SCAN + 1) * 4);
    int*   ci     = (int*)alloc((size_t)EE * 4);
    float* cv     = (float*)alloc((size_t)EE * 4);
    bf2*   P      = (bf2*)alloc((size_t)NN * 96 * 4);
    bf2*   R1     = (bf2*)alloc((size_t)NN * 72 * 4);
    bf2*   R2     = (bf2*)alloc((size_t)NN * 48 * 4);
    bf2*   R3     = (bf2*)alloc((size_t)NN * 24 * 4);
    bf2*   H0     = (bf2*)alloc((size_t)NN * 24 * 4);
    bf2*   H123   = (bf2*)alloc((size_t)NN * 72 * 4);
    bf2*   U1     = (bf2*)alloc((size_t)NN * 72 * 4);
    bf2*   U2     = (bf2*)alloc((size_t)NN * 48 * 4);
    bf2*   U3     = (bf2*)alloc((size_t)NN * 24 * 4);
    unsigned short* WoutT = (unsigned short*)alloc((size_t)48 * 480 * 2);

    hipMemsetAsync(cnt, 0, (size_t)NN * 4, stream);

    int gE = (EE + 255) / 256;
    int gN = (NN + 255) / 256;

    k_hist<<<gE, 256, 0, stream>>>(er, cnt);
    k_dinv<<<gN, 256, 0, stream>>>(cnt, dinv);
    k_scan1<<<NB_SCAN, 1024, 0, stream>>>(cnt, rp, bsum);
    k_scan2<<<1, 64, 0, stream>>>(bsum);
    k_scan3<<<gN, 256, 0, stream>>>(rp, cursor, bsum);
    k_fill<<<gE, 256, 0, stream>>>(er, ec, dinv, cursor, ci, cv);
    k_wt<<<(48 * 480 + 255) / 256, 256, 0, stream>>>(Wout, WoutT);

    int g64 = (NN + 63) / 64;
    k_proj<<<g64, 256, 0, stream>>>(x, W1, gamma, bn_var, P);

    int gW1 = (NN + 3) / 4;
    int gW2 = (NN + 7) / 8;
    k_spmm<72, 1><<<gW1, 256, 0, stream>>>(rp, ci, cv, dinv, P, 96, 24, R1, 72);
    k_spmm<48, 1><<<gW1, 256, 0, stream>>>(rp, ci, cv, dinv, R1, 72, 24, R2, 48);
    k_spmm<24, 2><<<gW2, 256, 0, stream>>>(rp, ci, cv, dinv, R2, 48, 24, R3, 24);

    k_bnrelu<<<(NN * 96 + 255) / 256, 256, 0, stream>>>(P, R1, R2, R3, b1, gamma, beta, bn_mean, bn_var, H0, H123);

    k_spmm<72, 1><<<gW1, 256, 0, stream>>>(rp, ci, cv, dinv, H123, 72, 0, U1, 72);
    k_spmm<48, 1><<<gW1, 256, 0, stream>>>(rp, ci, cv, dinv, U1, 72, 24, U2, 48);
    k_spmm<24, 2><<<gW2, 256, 0, stream>>>(rp, ci, cv, dinv, U2, 48, 24, U3, 24);

    k_cellout<<<NUNITS, 128, 0, stream>>>(H0, U1, U2, U3, W2, b2v, outcell);
    k_final_mfma<<<g64, 256, 0, stream>>>(outcell, WoutT, bout, out);
}

// Round 8
// 457.772 us; speedup vs baseline: 2.8022x; 1.2057x over previous
//
#include <hip/hip_runtime.h>
#include <hip/hip_bf16.h>

#define NN 50000
#define EE 800000
#define DD 100
#define HH 16
#define CC 40
#define NCELL 12
#define NB_SCAN 49   // ceil(50000/1024)

typedef __hip_bfloat162 bf2;
typedef short bf16x8 __attribute__((ext_vector_type(8)));
typedef float f32x4 __attribute__((ext_vector_type(4)));

__device__ __forceinline__ float2 b2f2(bf2 v) { return __bfloat1622float2(v); }
__device__ __forceinline__ bf2 f22b2(float f0, float f1) {
    float2 t; t.x = f0; t.y = f1;
    return __float22bfloat162_rn(t);
}
__device__ __forceinline__ unsigned short f2b(float f) {
    __hip_bfloat16 h = __float2bfloat16(f);
    return *reinterpret_cast<unsigned short*>(&h);
}

// ---------------- graph preprocessing ----------------

__global__ __launch_bounds__(256) void k_hist(const int* __restrict__ er, int* __restrict__ cnt) {
    int e = blockIdx.x * 256 + threadIdx.x;
    if (e < EE) atomicAdd(&cnt[er[e]], 1);
}

__global__ __launch_bounds__(256) void k_dinv(const int* __restrict__ cnt, float* __restrict__ dinv) {
    int i = blockIdx.x * 256 + threadIdx.x;
    if (i < NN) dinv[i] = rsqrtf((float)(cnt[i] + 1));   // +1 self loop
}

__global__ __launch_bounds__(1024) void k_scan1(const int* __restrict__ cnt, int* __restrict__ rp,
                                                int* __restrict__ bsum) {
    __shared__ int lds[1024];
    int t = threadIdx.x, i = blockIdx.x * 1024 + t;
    int v = (i < NN) ? cnt[i] : 0;
    lds[t] = v;
    __syncthreads();
    #pragma unroll
    for (int off = 1; off < 1024; off <<= 1) {
        int x = lds[t];
        int y = (t >= off) ? lds[t - off] : 0;
        __syncthreads();
        lds[t] = x + y;
        __syncthreads();
    }
    if (i < NN) rp[i] = lds[t] - v;
    if (t == 1023) bsum[blockIdx.x] = lds[1023];
}

__global__ __launch_bounds__(64) void k_scan2(int* __restrict__ bsum) {
    int t = threadIdx.x;
    int orig = (t < NB_SCAN) ? bsum[t] : 0;
    int v = orig;
    #pragma unroll
    for (int off = 1; off < 64; off <<= 1) {
        int y = __shfl_up(v, off);
        if (t >= off) v += y;
    }
    if (t < NB_SCAN) bsum[t] = v - orig;
    if (t == NB_SCAN - 1) bsum[NB_SCAN] = v;
}

__global__ __launch_bounds__(256) void k_scan3(int* __restrict__ rp, int* __restrict__ cursor,
                                               const int* __restrict__ bsum) {
    int i = blockIdx.x * 256 + threadIdx.x;
    if (i < NN) {
        int v = rp[i] + bsum[i >> 10];
        rp[i] = v;
        cursor[i] = v;
    }
    if (i == 0) rp[NN] = bsum[NB_SCAN];
}

__global__ __launch_bounds__(256) void k_fill(const int* __restrict__ er, const int* __restrict__ ec,
                                              const float* __restrict__ dinv, int* __restrict__ cursor,
                                              int* __restrict__ ci, float* __restrict__ cv) {
    int e = blockIdx.x * 256 + threadIdx.x;
    if (e >= EE) return;
    int r = er[e], c = ec[e];
    int p = atomicAdd(&cursor[r], 1);
    ci[p] = c;
    cv[p] = dinv[r] * dinv[c];
}

// ---------------- x row-normalize -> bf16 [N,128] (zero-padded) ----------------
// wave per node; lane handles cols 2l, 2l+1
__global__ __launch_bounds__(256) void k_normx(const float* __restrict__ x, bf2* __restrict__ xb) {
    int wid = (blockIdx.x * 256 + threadIdx.x) >> 6;
    int lane = threadIdx.x & 63;
    if (wid >= NN) return;
    const size_t base = (size_t)wid * DD;
    int c0 = 2 * lane;
    float a = (c0 < DD) ? x[base + c0] : 0.f;
    float b = (c0 + 1 < DD) ? x[base + c0 + 1] : 0.f;
    float ss = a * a + b * b;
    #pragma unroll
    for (int off = 1; off < 64; off <<= 1) ss += __shfl_xor(ss, off);
    float inv = 1.f / fmaxf(sqrtf(ss), 1e-12f);
    xb[(size_t)wid * 64 + lane] = f22b2(a * inv, b * inv);
}

// ---------------- W1T: [192][128] bf16, BN-scale folded, zero-padded K ----------------
__global__ __launch_bounds__(256) void k_w1t(const float* __restrict__ W1, const float* __restrict__ gamma,
                                             const float* __restrict__ bn_var, unsigned short* __restrict__ W1T) {
    int idx = blockIdx.x * 256 + threadIdx.x;
    if (idx >= 192 * 128) return;
    int c = idx / 128, k = idx % 128;
    int g = c / 48, i = c % 48;              // h = g
    int cell = (i / 16) * 4 + g, j = i % 16;
    float sc = gamma[cell * HH + j] * rsqrtf(bn_var[cell * HH + j] + 1e-5f);
    float v = (k < DD) ? W1[((size_t)cell * DD + k) * HH + j] * sc : 0.f;
    W1T[idx] = f2b(v);
}

// ---------------- projection via MFMA: P = xb @ W1T^T, bf16 out ----------------
// block 256 = 4 waves; wave = 16 rows x 12 col-tiles x 4 K-steps
__global__ __launch_bounds__(256) void k_proj_mfma(const bf2* __restrict__ xb,
                                                   const unsigned short* __restrict__ W1T,
                                                   unsigned short* __restrict__ Pu) {
    int tid = threadIdx.x;
    int wid = tid >> 6, lane = tid & 63;
    int rowbase = blockIdx.x * 64 + wid * 16;
    int arow = rowbase + (lane & 15);
    int arow_c = (arow < NN) ? arow : NN - 1;
    int kgrp = lane >> 4;
    int bcol = lane & 15;

    f32x4 acc[12];
    #pragma unroll
    for (int t = 0; t < 12; t++) acc[t] = (f32x4){0.f, 0.f, 0.f, 0.f};

    const unsigned short* ap = (const unsigned short*)(xb + (size_t)arow_c * 64);
    for (int kt = 0; kt < 4; kt++) {
        int k0 = kt * 32 + kgrp * 8;
        bf16x8 afr = *(const bf16x8*)(ap + k0);
        #pragma unroll
        for (int t = 0; t < 12; t++) {
            bf16x8 bfr = *(const bf16x8*)(W1T + (size_t)(t * 16 + bcol) * 128 + k0);
            acc[t] = __builtin_amdgcn_mfma_f32_16x16x32_bf16(afr, bfr, acc[t], 0, 0, 0);
        }
    }
    // D: col = lane&15, row = (lane>>4)*4 + r
    int drow = rowbase + (lane >> 4) * 4;
    #pragma unroll
    for (int r = 0; r < 4; r++) {
        int grow = drow + r;
        if (grow < NN) {
            unsigned short* pr = Pu + (size_t)grow * 192;
            #pragma unroll
            for (int t = 0; t < 12; t++)
                pr[t * 16 + (lane & 15)] = f2b(acc[t][r]);
        }
    }
}

// ---------------- SpMM bf16 ----------------
template <int NU, int RPW>
__global__ __launch_bounds__(256) void k_spmm(const int* __restrict__ rp, const int* __restrict__ ci,
                                              const float* __restrict__ cv, const float* __restrict__ dinv,
                                              const bf2* __restrict__ in, int ins, int ioff,
                                              bf2* __restrict__ out, int outs) {
    constexpr int LPR = (RPW == 1) ? 64 : 32;
    constexpr int J = (NU + LPR - 1) / LPR;
    int gw = (blockIdx.x * 256 + threadIdx.x) >> 6;
    int lane = threadIdx.x & 63;
    int sub = (RPW == 2) ? (lane >> 5) : 0;
    int su = (RPW == 2) ? (lane & 31) : lane;
    int row = gw * RPW + sub;
    if (row >= NN) return;
    const bf2* ib = in + ioff;

    float d = dinv[row];
    float sw = d * d;
    float2 acc[J];
    {
        size_t b = (size_t)row * ins;
        #pragma unroll
        for (int j = 0; j < J; j++) {
            int u = su + LPR * j;
            if (u < NU) {
                float2 f = b2f2(ib[b + u]);
                acc[j].x = sw * f.x; acc[j].y = sw * f.y;
            } else { acc[j].x = 0.f; acc[j].y = 0.f; }
        }
    }
    int s = rp[row], e = rp[row + 1];
    int p = s;
    int e4 = s + ((e - s) & ~3);
    while (p < e4) {
        int c0 = ci[p], c1 = ci[p + 1], c2 = ci[p + 2], c3 = ci[p + 3];
        float v0 = cv[p], v1 = cv[p + 1], v2 = cv[p + 2], v3 = cv[p + 3];
        bf2 r0[J], r1[J], r2[J], r3[J];
        size_t b0 = (size_t)c0 * ins, b1 = (size_t)c1 * ins, b2 = (size_t)c2 * ins, b3 = (size_t)c3 * ins;
        #pragma unroll
        for (int j = 0; j < J; j++) {
            int u = su + LPR * j;
            if (u < NU) {
                r0[j] = ib[b0 + u]; r1[j] = ib[b1 + u];
                r2[j] = ib[b2 + u]; r3[j] = ib[b3 + u];
            }
        }
        #pragma unroll
        for (int j = 0; j < J; j++) {
            int u = su + LPR * j;
            if (u < NU) {
                float2 f0 = b2f2(r0[j]), f1 = b2f2(r1[j]), f2 = b2f2(r2[j]), f3 = b2f2(r3[j]);
                acc[j].x += v0 * f0.x + v1 * f1.x + v2 * f2.x + v3 * f3.x;
                acc[j].y += v0 * f0.y + v1 * f1.y + v2 * f2.y + v3 * f3.y;
            }
        }
        p += 4;
    }
    while (p < e) {
        int c = ci[p];
        float v = cv[p];
        size_t b = (size_t)c * ins;
        #pragma unroll
        for (int j = 0; j < J; j++) {
            int u = su + LPR * j;
            if (u < NU) {
                float2 f = b2f2(ib[b + u]);
                acc[j].x += v * f.x; acc[j].y += v * f.y;
            }
        }
        p++;
    }
    size_t ob = (size_t)row * outs;
    #pragma unroll
    for (int j = 0; j < J; j++) {
        int u = su + LPR * j;
        if (u < NU) out[ob + u] = f22b2(acc[j].x, acc[j].y);
    }
}

// ---------------- BN shift + ReLU ----------------
__global__ __launch_bounds__(256) void k_bnrelu(const bf2* __restrict__ P, const bf2* __restrict__ R1,
                                                const bf2* __restrict__ R2, const bf2* __restrict__ R3,
                                                const float* __restrict__ b1, const float* __restrict__ gamma,
                                                const float* __restrict__ beta, const float* __restrict__ bn_mean,
                                                const float* __restrict__ bn_var,
                                                bf2* __restrict__ H0, bf2* __restrict__ H123) {
    int idx = blockIdx.x * 256 + threadIdx.x;
    if (idx >= NN * 96) return;
    int n = idx / 96, u = idx % 96;
    int h, su;
    bf2 v;
    if (u < 24) { h = 0; su = u; v = P[(size_t)n * 96 + su]; }
    else {
        int uu = u - 24;
        h = uu / 24 + 1; su = uu % 24;
        if (h == 1)      v = R1[(size_t)n * 72 + su];
        else if (h == 2) v = R2[(size_t)n * 48 + su];
        else             v = R3[(size_t)n * 24 + su];
    }
    int c0 = 2 * su;
    int cell = (c0 / 16) * 4 + h;
    int j0 = c0 % 16;
    int i0 = cell * HH + j0, i1 = i0 + 1;
    float s0 = gamma[i0] * rsqrtf(bn_var[i0] + 1e-5f);
    float s1 = gamma[i1] * rsqrtf(bn_var[i1] + 1e-5f);
    float sh0 = (b1[i0] - bn_mean[i0]) * s0 + beta[i0];
    float sh1 = (b1[i1] - bn_mean[i1]) * s1 + beta[i1];
    float2 f = b2f2(v);
    bf2 o = f22b2(fmaxf(f.x + sh0, 0.f), fmaxf(f.y + sh1, 0.f));
    if (u < 24) H0[(size_t)n * 24 + u] = o;
    else        H123[(size_t)n * 72 + (u - 24)] = o;
}

// ---------------- cell outputs: weight-in-register, wave-pair per node ----------------
#define NUNITS 1024
__global__ __launch_bounds__(128) void k_cellout(const bf2* __restrict__ H0, const bf2* __restrict__ U1,
                                                 const bf2* __restrict__ U2, const bf2* __restrict__ U3,
                                                 const float* __restrict__ W2, const float* __restrict__ b2v,
                                                 float* __restrict__ outcell) {
    __shared__ float row[2][200];
    int tid = threadIdx.x;
    int gid = tid;
    bool act = gid < 120;
    int cell = act ? gid / 10 : 0;
    int cc = act ? (4 * gid) % 40 : 0;
    int h = cell & 3, r = cell >> 2;
    float4 wreg[HH];
    float4 bias = make_float4(0.f, 0.f, 0.f, 0.f);
    if (act) {
        #pragma unroll
        for (int k = 0; k < HH; k++)
            wreg[k] = *(const float4*)(W2 + (size_t)cell * (HH * CC) + k * CC + cc);
        bias = *(const float4*)(b2v + cell * CC + cc);
    }
    int colbase = h * 48 + r * 16;

    const bf2* tabs[4] = {H0, U1, U2, U3};
    const int strides[4] = {24, 72, 48, 24};

    int iters = (NN + NUNITS - 1) / NUNITS;
    int n_cur = blockIdx.x;
    if (tid < 96 && n_cur < NN) {
        int t4 = tid / 24, uu = tid % 24;
        float2 f = b2f2(tabs[t4][(size_t)n_cur * strides[t4] + uu]);
        row[0][t4 * 48 + 2 * uu] = f.x;
        row[0][t4 * 48 + 2 * uu + 1] = f.y;
    }
    __syncthreads();
    for (int it = 0; it < iters; it++) {
        int buf = it & 1;
        int n_next = n_cur + NUNITS;
        if (it + 1 < iters && tid < 96 && n_next < NN) {
            int t4 = tid / 24, uu = tid % 24;
            float2 f = b2f2(tabs[t4][(size_t)n_next * strides[t4] + uu]);
            row[buf ^ 1][t4 * 48 + 2 * uu] = f.x;
            row[buf ^ 1][t4 * 48 + 2 * uu + 1] = f.y;
        }
        if (act && n_cur < NN) {
            float4 acc = bias;
            #pragma unroll
            for (int k = 0; k < HH; k++) {
                float xv = row[buf][colbase + k];
                acc.x += xv * wreg[k].x;
                acc.y += xv * wreg[k].y;
                acc.z += xv * wreg[k].z;
                acc.w += xv * wreg[k].w;
            }
            *(float4*)(outcell + (size_t)n_cur * (NCELL * CC) + 4 * gid) = acc;
        }
        __syncthreads();
        n_cur = n_next;
    }
}

// ---------------- Wout pre-transpose: WoutT[48][480] bf16, zero-padded ----------------
__global__ __launch_bounds__(256) void k_wt(const float* __restrict__ Wout, unsigned short* __restrict__ WoutT) {
    int idx = blockIdx.x * 256 + threadIdx.x;
    if (idx >= 48 * 480) return;
    int c = idx / 480, k = idx % 480;
    float v = (c < CC) ? Wout[(size_t)k * CC + c] : 0.f;
    WoutT[idx] = f2b(v);
}

// ---------------- final: MFMA GEMM  out = relu(cell) @ Wout + bout ----------------
__global__ __launch_bounds__(256) void k_final_mfma(const float* __restrict__ cell,
                                                    const unsigned short* __restrict__ WoutT,
                                                    const float* __restrict__ bout, float* __restrict__ out) {
    int tid = threadIdx.x;
    int wid = tid >> 6, lane = tid & 63;
    int rowbase = blockIdx.x * 64 + wid * 16;
    int arow = rowbase + (lane & 15);
    int arow_c = (arow < NN) ? arow : NN - 1;
    int kgrp = lane >> 4;

    f32x4 acc0 = {0.f, 0.f, 0.f, 0.f};
    f32x4 acc1 = {0.f, 0.f, 0.f, 0.f};
    f32x4 acc2 = {0.f, 0.f, 0.f, 0.f};

    const float* arow_p = cell + (size_t)arow_c * (NCELL * CC);
    int bcol = lane & 15;

    for (int kt = 0; kt < 15; kt++) {
        int k0 = kt * 32 + kgrp * 8;
        float4 va = *(const float4*)(arow_p + k0);
        float4 vb = *(const float4*)(arow_p + k0 + 4);
        bf16x8 afr;
        afr[0] = (short)f2b(fmaxf(va.x, 0.f));
        afr[1] = (short)f2b(fmaxf(va.y, 0.f));
        afr[2] = (short)f2b(fmaxf(va.z, 0.f));
        afr[3] = (short)f2b(fmaxf(va.w, 0.f));
        afr[4] = (short)f2b(fmaxf(vb.x, 0.f));
        afr[5] = (short)f2b(fmaxf(vb.y, 0.f));
        afr[6] = (short)f2b(fmaxf(vb.z, 0.f));
        afr[7] = (short)f2b(fmaxf(vb.w, 0.f));
        bf16x8 bf0 = *(const bf16x8*)(WoutT + (size_t)(0 * 16 + bcol) * 480 + k0);
        bf16x8 bf1 = *(const bf16x8*)(WoutT + (size_t)(1 * 16 + bcol) * 480 + k0);
        bf16x8 bf2f = *(const bf16x8*)(WoutT + (size_t)(2 * 16 + bcol) * 480 + k0);
        acc0 = __builtin_amdgcn_mfma_f32_16x16x32_bf16(afr, bf0, acc0, 0, 0, 0);
        acc1 = __builtin_amdgcn_mfma_f32_16x16x32_bf16(afr, bf1, acc1, 0, 0, 0);
        acc2 = __builtin_amdgcn_mfma_f32_16x16x32_bf16(afr, bf2f, acc2, 0, 0, 0);
    }

    int drow = rowbase + (lane >> 4) * 4;
    #pragma unroll
    for (int r = 0; r < 4; r++) {
        int grow = drow + r;
        if (grow < NN) {
            int c0 = 0 * 16 + (lane & 15);
            int c1 = 1 * 16 + (lane & 15);
            int c2 = 2 * 16 + (lane & 15);
            float* o = out + (size_t)grow * CC;
            o[c0] = acc0[r] + bout[c0];
            o[c1] = acc1[r] + bout[c1];
            if (c2 < CC) o[c2] = acc2[r] + bout[c2];
        }
    }
}

// ---------------- host ----------------

extern "C" void kernel_launch(void* const* d_in, const int* in_sizes, int n_in,
                              void* d_out, int out_size, void* d_ws, size_t ws_size,
                              hipStream_t stream) {
    const float* x       = (const float*)d_in[0];
    const int*   er      = (const int*)d_in[1];
    const int*   ec      = (const int*)d_in[2];
    const float* W1      = (const float*)d_in[3];
    const float* b1      = (const float*)d_in[4];
    const float* gamma   = (const float*)d_in[5];
    const float* beta    = (const float*)d_in[6];
    const float* bn_mean = (const float*)d_in[7];
    const float* bn_var  = (const float*)d_in[8];
    const float* W2      = (const float*)d_in[9];
    const float* b2v     = (const float*)d_in[10];
    const float* Wout    = (const float*)d_in[11];
    const float* bout    = (const float*)d_in[12];

    float* out     = (float*)d_out;               // [N, C] f32
    float* outcell = out + (size_t)NN * CC;       // [N, NC, C] f32

    char* w = (char*)d_ws;
    auto alloc = [&](size_t bytes) {
        void* p = (void*)w;
        w += (bytes + 255) & ~(size_t)255;
        return p;
    };
    int*   cnt    = (int*)alloc((size_t)NN * 4);
    int*   rp     = (int*)alloc((size_t)(NN + 1) * 4);
    int*   cursor = (int*)alloc((size_t)NN * 4);
    float* dinv   = (float*)alloc((size_t)NN * 4);
    int*   bsum   = (int*)alloc((size_t)(NB_SCAN + 1) * 4);
    int*   ci     = (int*)alloc((size_t)EE * 4);
    float* cv     = (float*)alloc((size_t)EE * 4);
    bf2*   xb     = (bf2*)alloc((size_t)NN * 64 * 4);   // [N,128] bf16
    bf2*   P      = (bf2*)alloc((size_t)NN * 96 * 4);   // [N,192] bf16
    bf2*   R1     = (bf2*)alloc((size_t)NN * 72 * 4);
    bf2*   R2     = (bf2*)alloc((size_t)NN * 48 * 4);
    bf2*   R3     = (bf2*)alloc((size_t)NN * 24 * 4);
    bf2*   H0     = (bf2*)alloc((size_t)NN * 24 * 4);
    bf2*   H123   = (bf2*)alloc((size_t)NN * 72 * 4);
    bf2*   U1     = (bf2*)alloc((size_t)NN * 72 * 4);
    bf2*   U2     = (bf2*)alloc((size_t)NN * 48 * 4);
    bf2*   U3     = (bf2*)alloc((size_t)NN * 24 * 4);
    unsigned short* WoutT = (unsigned short*)alloc((size_t)48 * 480 * 2);
    unsigned short* W1T   = (unsigned short*)alloc((size_t)192 * 128 * 2);

    hipMemsetAsync(cnt, 0, (size_t)NN * 4, stream);

    int gE = (EE + 255) / 256;
    int gN = (NN + 255) / 256;

    k_hist<<<gE, 256, 0, stream>>>(er, cnt);
    k_dinv<<<gN, 256, 0, stream>>>(cnt, dinv);
    k_scan1<<<NB_SCAN, 1024, 0, stream>>>(cnt, rp, bsum);
    k_scan2<<<1, 64, 0, stream>>>(bsum);
    k_scan3<<<gN, 256, 0, stream>>>(rp, cursor, bsum);
    k_fill<<<gE, 256, 0, stream>>>(er, ec, dinv, cursor, ci, cv);
    k_wt<<<(48 * 480 + 255) / 256, 256, 0, stream>>>(Wout, WoutT);
    k_w1t<<<(192 * 128 + 255) / 256, 256, 0, stream>>>(W1, gamma, bn_var, W1T);

    int gW = (NN + 3) / 4;         // wave per node
    int g64 = (NN + 63) / 64;
    k_normx<<<gW, 256, 0, stream>>>(x, xb);
    k_proj_mfma<<<g64, 256, 0, stream>>>(xb, W1T, (unsigned short*)P);

    int gW1 = (NN + 3) / 4;
    int gW2 = (NN + 7) / 8;
    k_spmm<72, 1><<<gW1, 256, 0, stream>>>(rp, ci, cv, dinv, P, 96, 24, R1, 72);
    k_spmm<48, 1><<<gW1, 256, 0, stream>>>(rp, ci, cv, dinv, R1, 72, 24, R2, 48);
    k_spmm<24, 2><<<gW2, 256, 0, stream>>>(rp, ci, cv, dinv, R2, 48, 24, R3, 24);

    k_bnrelu<<<(NN * 96 + 255) / 256, 256, 0, stream>>>(P, R1, R2, R3, b1, gamma, beta, bn_mean, bn_var, H0, H123);

    k_spmm<72, 1><<<gW1, 256, 0, stream>>>(rp, ci, cv, dinv, H123, 72, 0, U1, 72);
    k_spmm<48, 1><<<gW1, 256, 0, stream>>>(rp, ci, cv, dinv, U1, 72, 24, U2, 48);
    k_spmm<24, 2><<<gW2, 256, 0, stream>>>(rp, ci, cv, dinv, U2, 48, 24, U3, 24);

    k_cellout<<<NUNITS, 128, 0, stream>>>(H0, U1, U2, U3, W2, b2v, outcell);
    k_final_mfma<<<g64, 256, 0, stream>>>(outcell, WoutT, bout, out);
}